// Round 9
// baseline (252.849 us; speedup 1.0000x reference)
//
#include <hip/hip_runtime.h>
#include <hip/hip_bf16.h>

// GCN regressor: 3x GCNConv(64->64, normalize=False) + mean-pool + MLP(64->32->16->1)
// Round 7 kernel (resubmitted unchanged; container failures in rounds 7-8):
// agg_fused gets 32 lanes/node (two 16-lane halves over even/odd edges,
// each unrolled x4) -> 8 independent gathers in flight per node, 2x grid.
// Halves combined via one __shfl_xor before the MLP epilogue. Build/pool/head
// unchanged (round-6 counting-sort CSR).

#define HID 64
#define KNBLK 256   // partition blocks for hist/scatter passes (must be 256: scanB1 scans 256)

// ---- pass A: per-block, per-bucket histogram. bucket = dst >> 8 ----
__global__ __launch_bounds__(256) void histA_kernel(const int* __restrict__ ei,
                                                    int* __restrict__ counts,
                                                    int E, int K, int chunk) {
    __shared__ int hist[256];
    int t = threadIdx.x, b = blockIdx.x;
    hist[t] = 0;
    __syncthreads();
    int s = b * chunk, e1 = min(E, s + chunk);
    for (int i = s + t; i < e1; i += 256)
        atomicAdd(&hist[ei[E + i] >> 8], 1);
    __syncthreads();
    if (t < K) counts[b * K + t] = hist[t];
}

// ---- scan B1: per bucket k, exclusive scan of counts[blk][k] over blk=0..255 ----
__global__ __launch_bounds__(256) void scanB1_kernel(int* __restrict__ counts,
                                                     int* __restrict__ btot, int K) {
    __shared__ int sh[256];
    int k = blockIdx.x, t = threadIdx.x;
    int v = counts[t * K + k];
    sh[t] = v;
    __syncthreads();
    #pragma unroll
    for (int d = 1; d < 256; d <<= 1) {
        int add = (t >= d) ? sh[t - d] : 0;
        __syncthreads();
        sh[t] += add;
        __syncthreads();
    }
    counts[t * K + k] = sh[t] - v;          // exclusive over blocks
    if (t == 255) btot[k] = sh[255];        // bucket total
}

// ---- scan B2: exclusive scan of bucket totals -> bucket base offsets bb0[0..K] ----
__global__ __launch_bounds__(256) void scanB2_kernel(const int* __restrict__ btot,
                                                     int* __restrict__ bb0, int K) {
    __shared__ int sh[256];
    int t = threadIdx.x;
    int v = (t < K) ? btot[t] : 0;
    sh[t] = v;
    __syncthreads();
    #pragma unroll
    for (int d = 1; d < 256; d <<= 1) {
        int add = (t >= d) ? sh[t - d] : 0;
        __syncthreads();
        sh[t] += add;
        __syncthreads();
    }
    if (t < K) bb0[t] = sh[t] - v;
    if (t == 255) bb0[K] = sh[255];         // == E
}

// ---- pass B: scatter edges to bucket-partitioned ebuf (dense slice writes) ----
__global__ __launch_bounds__(256) void passB_kernel(const int* __restrict__ ei,
                                                    const float* __restrict__ ew,
                                                    const int* __restrict__ counts,
                                                    const int* __restrict__ bb0,
                                                    int4* __restrict__ ebuf,
                                                    int E, int K, int chunk) {
    __shared__ int lcur[256];
    int t = threadIdx.x, b = blockIdx.x;
    lcur[t] = 0;
    __syncthreads();
    int s = b * chunk, e1 = min(E, s + chunk);
    for (int i = s + t; i < e1; i += 256) {
        int src = ei[i];
        int dst = ei[E + i];
        float w = ew[i];
        int k = dst >> 8;
        int idx = atomicAdd(&lcur[k], 1);
        int slot = bb0[k] + counts[b * K + k] + idx;
        ebuf[slot] = make_int4(src, __float_as_int(w), dst, 0);
    }
}

// ---- pass C: per-bucket counting sort -> final CSR (int2{src,wbits}) + offs ----
__global__ __launch_bounds__(256) void passC_kernel(const int4* __restrict__ ebuf,
                                                    const int* __restrict__ bb0,
                                                    int2* __restrict__ csr,
                                                    int* __restrict__ offs,
                                                    int N, int E, int K) {
    __shared__ int ldeg[256];
    __shared__ int sh[256];
    __shared__ int lofs[256];
    int b = blockIdx.x, t = threadIdx.x;
    int gb0 = bb0[b], gb1 = bb0[b + 1];
    int cnt = gb1 - gb0;
    int base = b << 8;
    ldeg[t] = 0;
    __syncthreads();
    for (int i = t; i < cnt; i += 256)
        atomicAdd(&ldeg[ebuf[gb0 + i].z & 255], 1);
    __syncthreads();
    int v = ldeg[t];
    sh[t] = v;
    __syncthreads();
    #pragma unroll
    for (int d = 1; d < 256; d <<= 1) {
        int add = (t >= d) ? sh[t - d] : 0;
        __syncthreads();
        sh[t] += add;
        __syncthreads();
    }
    lofs[t] = sh[t] - v;                      // exclusive local offset (also cursor below)
    int nInB = min(256, N - base);
    if (t < nInB) offs[base + t] = gb0 + lofs[t];
    if (b == K - 1 && t == 0) offs[N] = E;
    __syncthreads();
    for (int i = t; i < cnt; i += 256) {
        int4 r = ebuf[gb0 + i];
        int d = r.z & 255;
        int pos = atomicAdd(&lofs[d], 1);     // reuse lofs as cursor
        csr[gb0 + pos] = make_int2(r.x, r.y);
    }
}

// Fused layer: out[n][:] = relu( (sum_{e in CSR(n)} w_e * prev[src_e][:]) @ W + b )
// 32 lanes per node: halves (lanes 0-15 / 16-31 of each 32-cluster) walk
// even/odd edges, each unrolled x4 -> 8 gathers in flight per node.
// Lane l (=tid&15) owns channels 4l..4l+3. Combine halves via shfl_xor(16,32).
__global__ __launch_bounds__(256) void agg_fused_kernel(const float* __restrict__ prev,
                                                        const int2* __restrict__ csr,
                                                        const int* __restrict__ offs,
                                                        const float* __restrict__ W,
                                                        const float* __restrict__ bias,
                                                        float* __restrict__ out, int N) {
    __shared__ float Wl[64 * 64];
    __shared__ float bl[64];
    for (int i = threadIdx.x; i < 64 * 64; i += 256) Wl[i] = W[i];
    if (threadIdx.x < 64) bl[threadIdx.x] = bias[threadIdx.x];
    __syncthreads();

    int g = (blockIdx.x * 256 + threadIdx.x) >> 5;   // node (32 lanes each)
    int l = threadIdx.x & 15;                        // channel lane
    int half = (threadIdx.x >> 4) & 1;               // even/odd edge half
    if (g >= N) return;                              // no further __syncthreads below

    int e0 = offs[g], e1 = offs[g + 1];
    float4 acc = make_float4(0.f, 0.f, 0.f, 0.f);
    int e = e0 + half;
    for (; e + 6 < e1; e += 8) {
        // 4 independent records for this half (stride 2) -> 4 gathers in flight
        int2 r0 = csr[e + 0];
        int2 r1 = csr[e + 2];
        int2 r2 = csr[e + 4];
        int2 r3 = csr[e + 6];
        const float4 v0 = *reinterpret_cast<const float4*>(prev + (size_t)r0.x * 64 + l * 4);
        const float4 v1 = *reinterpret_cast<const float4*>(prev + (size_t)r1.x * 64 + l * 4);
        const float4 v2 = *reinterpret_cast<const float4*>(prev + (size_t)r2.x * 64 + l * 4);
        const float4 v3 = *reinterpret_cast<const float4*>(prev + (size_t)r3.x * 64 + l * 4);
        const float w0 = __int_as_float(r0.y);
        const float w1 = __int_as_float(r1.y);
        const float w2 = __int_as_float(r2.y);
        const float w3 = __int_as_float(r3.y);
        acc.x = fmaf(w0, v0.x, acc.x); acc.y = fmaf(w0, v0.y, acc.y);
        acc.z = fmaf(w0, v0.z, acc.z); acc.w = fmaf(w0, v0.w, acc.w);
        acc.x = fmaf(w1, v1.x, acc.x); acc.y = fmaf(w1, v1.y, acc.y);
        acc.z = fmaf(w1, v1.z, acc.z); acc.w = fmaf(w1, v1.w, acc.w);
        acc.x = fmaf(w2, v2.x, acc.x); acc.y = fmaf(w2, v2.y, acc.y);
        acc.z = fmaf(w2, v2.z, acc.z); acc.w = fmaf(w2, v2.w, acc.w);
        acc.x = fmaf(w3, v3.x, acc.x); acc.y = fmaf(w3, v3.y, acc.y);
        acc.z = fmaf(w3, v3.z, acc.z); acc.w = fmaf(w3, v3.w, acc.w);
    }
    for (; e < e1; e += 2) {
        int2 rec = csr[e];
        float w = __int_as_float(rec.y);
        const float4 v = *reinterpret_cast<const float4*>(prev + (size_t)rec.x * 64 + l * 4);
        acc.x = fmaf(w, v.x, acc.x);
        acc.y = fmaf(w, v.y, acc.y);
        acc.z = fmaf(w, v.z, acc.z);
        acc.w = fmaf(w, v.w, acc.w);
    }
    // combine halves: after this, both halves hold the full per-node sum
    acc.x += __shfl_xor(acc.x, 16, 32);
    acc.y += __shfl_xor(acc.y, 16, 32);
    acc.z += __shfl_xor(acc.z, 16, 32);
    acc.w += __shfl_xor(acc.w, 16, 32);

    const float4 b4 = *reinterpret_cast<const float4*>(bl + l * 4);
    float4 o = b4;
    #pragma unroll
    for (int k2 = 0; k2 < 16; ++k2) {
        float c0 = __shfl(acc.x, k2, 16);
        float c1 = __shfl(acc.y, k2, 16);
        float c2 = __shfl(acc.z, k2, 16);
        float c3 = __shfl(acc.w, k2, 16);
        const float4 w0 = *reinterpret_cast<const float4*>(Wl + (4 * k2 + 0) * 64 + l * 4);
        const float4 w1 = *reinterpret_cast<const float4*>(Wl + (4 * k2 + 1) * 64 + l * 4);
        const float4 w2 = *reinterpret_cast<const float4*>(Wl + (4 * k2 + 2) * 64 + l * 4);
        const float4 w3 = *reinterpret_cast<const float4*>(Wl + (4 * k2 + 3) * 64 + l * 4);
        o.x = fmaf(c0, w0.x, o.x); o.y = fmaf(c0, w0.y, o.y);
        o.z = fmaf(c0, w0.z, o.z); o.w = fmaf(c0, w0.w, o.w);
        o.x = fmaf(c1, w1.x, o.x); o.y = fmaf(c1, w1.y, o.y);
        o.z = fmaf(c1, w1.z, o.z); o.w = fmaf(c1, w1.w, o.w);
        o.x = fmaf(c2, w2.x, o.x); o.y = fmaf(c2, w2.y, o.y);
        o.z = fmaf(c2, w2.z, o.z); o.w = fmaf(c2, w2.w, o.w);
        o.x = fmaf(c3, w3.x, o.x); o.y = fmaf(c3, w3.y, o.y);
        o.z = fmaf(c3, w3.z, o.z); o.w = fmaf(c3, w3.w, o.w);
    }
    if (half == 0) {
        float4 r;
        r.x = fmaxf(o.x, 0.f);
        r.y = fmaxf(o.y, 0.f);
        r.z = fmaxf(o.z, 0.f);
        r.w = fmaxf(o.w, 0.f);
        *reinterpret_cast<float4*>(out + (size_t)g * 64 + l * 4) = r;
    }
}

// Mean-pool stage 1: sorted batch -> register run-length accumulate, atomic flush.
__global__ __launch_bounds__(256) void pool_kernel(const float* __restrict__ a,
                                                   const int* __restrict__ batch,
                                                   float* __restrict__ sums,
                                                   float* __restrict__ cnts, int N) {
    int c = threadIdx.x & 63;
    int sub = threadIdx.x >> 6;   // 0..3
    int chunk = (N + gridDim.x - 1) / gridDim.x;
    int start = blockIdx.x * chunk;
    int end = min(N, start + chunk);
    int curg = -1;
    float acc = 0.f, cacc = 0.f;
    for (int n = start + sub; n < end; n += 4) {
        int g = batch[n];
        if (g != curg) {
            if (curg >= 0) {
                atomicAdd(&sums[curg * 64 + c], acc);
                if (c == 0) atomicAdd(&cnts[curg], cacc);
            }
            curg = g; acc = 0.f; cacc = 0.f;
        }
        acc += a[(size_t)n * 64 + c];
        cacc += 1.f;
    }
    if (curg >= 0) {
        atomicAdd(&sums[curg * 64 + c], acc);
        if (c == 0) atomicAdd(&cnts[curg], cacc);
    }
}

// MLP head: pooled[G][64] -> relu(@lw1 64x32) -> relu(@lw2 32x16) -> @lw3 16x1
__global__ __launch_bounds__(256) void head_kernel(const float* __restrict__ sums,
                                                   const float* __restrict__ cnts,
                                                   const float* __restrict__ lw1,
                                                   const float* __restrict__ lb1,
                                                   const float* __restrict__ lw2,
                                                   const float* __restrict__ lb2,
                                                   const float* __restrict__ lw3,
                                                   const float* __restrict__ lb3,
                                                   float* __restrict__ out, int G) {
    __shared__ float pooled[64 * 64];
    __shared__ float z1[64 * 32];
    __shared__ float z2[64 * 16];
    int tid = threadIdx.x;
    for (int i = tid; i < G * 64; i += 256) {
        int g = i >> 6;
        float cn = cnts[g];
        cn = (cn < 1.f) ? 1.f : cn;
        pooled[i] = sums[i] / cn;
    }
    __syncthreads();
    for (int i = tid; i < G * 32; i += 256) {
        int g = i >> 5, j = i & 31;
        float acc = lb1[j];
        #pragma unroll
        for (int k = 0; k < 64; ++k) acc = fmaf(pooled[g * 64 + k], lw1[k * 32 + j], acc);
        z1[i] = fmaxf(acc, 0.f);
    }
    __syncthreads();
    for (int i = tid; i < G * 16; i += 256) {
        int g = i >> 4, j = i & 15;
        float acc = lb2[j];
        #pragma unroll
        for (int k = 0; k < 32; ++k) acc = fmaf(z1[g * 32 + k], lw2[k * 16 + j], acc);
        z2[i] = fmaxf(acc, 0.f);
    }
    __syncthreads();
    if (tid < G) {
        float acc = lb3[0];
        #pragma unroll
        for (int k = 0; k < 16; ++k) acc = fmaf(z2[tid * 16 + k], lw3[k], acc);
        out[tid] = acc;
    }
}

static inline size_t align256(size_t x) { return (x + 255) & ~(size_t)255; }

extern "C" void kernel_launch(void* const* d_in, const int* in_sizes, int n_in,
                              void* d_out, int out_size, void* d_ws, size_t ws_size,
                              hipStream_t stream) {
    const float* x     = (const float*)d_in[0];
    const int*   ei    = (const int*)d_in[1];     // (2,E): [0..E)=src, [E..2E)=dst
    const float* ew    = (const float*)d_in[2];
    const int*   batch = (const int*)d_in[3];
    const float* W1 = (const float*)d_in[4];
    const float* b1 = (const float*)d_in[5];
    const float* W2 = (const float*)d_in[6];
    const float* b2 = (const float*)d_in[7];
    const float* W3 = (const float*)d_in[8];
    const float* b3 = (const float*)d_in[9];
    const float* lw1 = (const float*)d_in[10];
    const float* lb1 = (const float*)d_in[11];
    const float* lw2 = (const float*)d_in[12];
    const float* lb2 = (const float*)d_in[13];
    const float* lw3 = (const float*)d_in[14];
    const float* lb3 = (const float*)d_in[15];
    float* out = (float*)d_out;

    const int N = in_sizes[0] / 64;
    const int E = in_sizes[2];
    const int G = out_size;
    const int K = (N + 255) >> 8;          // buckets of 256 nodes
    const int chunk = (E + KNBLK - 1) / KNBLK;

    // Workspace carve
    char* w = (char*)d_ws;
    size_t off = 0;
    auto carve = [&](size_t bytes) -> void* {
        void* p = w + off;
        off = align256(off + bytes);
        return p;
    };
    float* bufA   = (float*)carve((size_t)N * 64 * 4);   // also aliases ebuf (dead before agg1)
    float* bufB   = (float*)carve((size_t)N * 64 * 4);
    int2*  csr    = (int2*)carve((size_t)E * 8);
    int*   counts = (int*)carve((size_t)KNBLK * K * 4);
    int*   btot   = (int*)carve((size_t)K * 4);
    int*   bb0    = (int*)carve((size_t)(K + 1) * 4);
    int*   offs   = (int*)carve((size_t)(N + 1) * 4);
    float* sums   = (float*)carve((size_t)G * 64 * 4);
    float* cnts   = (float*)carve((size_t)G * 4);
    int4*  ebuf   = (int4*)bufA;                         // 800K*16B = 12.8MB fits in bufA
    (void)ws_size; (void)n_in;

    hipMemsetAsync(sums, 0, (size_t)G * 64 * 4, stream);
    hipMemsetAsync(cnts, 0, (size_t)G * 4, stream);

    // ---- CSR build: bucketed counting sort (dense writes throughout) ----
    histA_kernel <<<KNBLK, 256, 0, stream>>>(ei, counts, E, K, chunk);
    scanB1_kernel<<<K,     256, 0, stream>>>(counts, btot, K);
    scanB2_kernel<<<1,     256, 0, stream>>>(btot, bb0, K);
    passB_kernel <<<KNBLK, 256, 0, stream>>>(ei, ew, counts, bb0, ebuf, E, K, chunk);
    passC_kernel <<<K,     256, 0, stream>>>(ebuf, bb0, csr, offs, N, E, K);

    const int AGG_BLOCKS = (int)(((size_t)N * 32 + 255) / 256);

    // ---- 3 fused layers: agg (raw features) -> @W + b -> relu ----
    agg_fused_kernel<<<AGG_BLOCKS, 256, 0, stream>>>(x,    csr, offs, W1, b1, bufA, N);
    agg_fused_kernel<<<AGG_BLOCKS, 256, 0, stream>>>(bufA, csr, offs, W2, b2, bufB, N);
    agg_fused_kernel<<<AGG_BLOCKS, 256, 0, stream>>>(bufB, csr, offs, W3, b3, bufA, N);

    // ---- pool + head ----
    pool_kernel<<<1024, 256, 0, stream>>>(bufA, batch, sums, cnts, N);
    head_kernel<<<1, 256, 0, stream>>>(sums, cnts, lw1, lb1, lw2, lb2, lw3, lb3, out, G);
}

// Round 10
// 218.927 us; speedup vs baseline: 1.1549x; 1.1549x over previous
//
#include <hip/hip_runtime.h>
#include <hip/hip_bf16.h>

// GCN regressor: 3x GCNConv(64->64, normalize=False) + mean-pool + MLP(64->32->16->1)
// Round 10: REVERT round-7 (32-lane agg regressed: occupancy 58->42, duplicated
// epilogue). NEW agg: edge-parallel bucket kernel.
//   - block = 64 consecutive dst nodes = contiguous CSR range (dst-sorted CSR)
//   - 16 groups x 16 lanes; group walks a contiguous edge chunk with register
//     run-length accumulation (uniform control flow in group -> no divergence),
//     flushes to LDS accum[64][65] via atomicAdd at node boundaries
//   - epilogue: 4 threads/node apply W (LDS) + bias + relu, write out
//   - csr.x packs src (low 16b, N<65536) | dst_local8 (bits 16-23): passC change
// Build/pool/head unchanged (round-6 counting-sort CSR).

#define HID 64
#define KNBLK 256   // partition blocks for hist/scatter passes (must be 256: scanB1 scans 256)

// ---- pass A: per-block, per-bucket histogram. bucket = dst >> 8 ----
__global__ __launch_bounds__(256) void histA_kernel(const int* __restrict__ ei,
                                                    int* __restrict__ counts,
                                                    int E, int K, int chunk) {
    __shared__ int hist[256];
    int t = threadIdx.x, b = blockIdx.x;
    hist[t] = 0;
    __syncthreads();
    int s = b * chunk, e1 = min(E, s + chunk);
    for (int i = s + t; i < e1; i += 256)
        atomicAdd(&hist[ei[E + i] >> 8], 1);
    __syncthreads();
    if (t < K) counts[b * K + t] = hist[t];
}

// ---- scan B1: per bucket k, exclusive scan of counts[blk][k] over blk=0..255 ----
__global__ __launch_bounds__(256) void scanB1_kernel(int* __restrict__ counts,
                                                     int* __restrict__ btot, int K) {
    __shared__ int sh[256];
    int k = blockIdx.x, t = threadIdx.x;
    int v = counts[t * K + k];
    sh[t] = v;
    __syncthreads();
    #pragma unroll
    for (int d = 1; d < 256; d <<= 1) {
        int add = (t >= d) ? sh[t - d] : 0;
        __syncthreads();
        sh[t] += add;
        __syncthreads();
    }
    counts[t * K + k] = sh[t] - v;          // exclusive over blocks
    if (t == 255) btot[k] = sh[255];        // bucket total
}

// ---- scan B2: exclusive scan of bucket totals -> bucket base offsets bb0[0..K] ----
__global__ __launch_bounds__(256) void scanB2_kernel(const int* __restrict__ btot,
                                                     int* __restrict__ bb0, int K) {
    __shared__ int sh[256];
    int t = threadIdx.x;
    int v = (t < K) ? btot[t] : 0;
    sh[t] = v;
    __syncthreads();
    #pragma unroll
    for (int d = 1; d < 256; d <<= 1) {
        int add = (t >= d) ? sh[t - d] : 0;
        __syncthreads();
        sh[t] += add;
        __syncthreads();
    }
    if (t < K) bb0[t] = sh[t] - v;
    if (t == 255) bb0[K] = sh[255];         // == E
}

// ---- pass B: scatter edges to bucket-partitioned ebuf (dense slice writes) ----
__global__ __launch_bounds__(256) void passB_kernel(const int* __restrict__ ei,
                                                    const float* __restrict__ ew,
                                                    const int* __restrict__ counts,
                                                    const int* __restrict__ bb0,
                                                    int4* __restrict__ ebuf,
                                                    int E, int K, int chunk) {
    __shared__ int lcur[256];
    int t = threadIdx.x, b = blockIdx.x;
    lcur[t] = 0;
    __syncthreads();
    int s = b * chunk, e1 = min(E, s + chunk);
    for (int i = s + t; i < e1; i += 256) {
        int src = ei[i];
        int dst = ei[E + i];
        float w = ew[i];
        int k = dst >> 8;
        int idx = atomicAdd(&lcur[k], 1);
        int slot = bb0[k] + counts[b * K + k] + idx;
        ebuf[slot] = make_int4(src, __float_as_int(w), dst, 0);
    }
}

// ---- pass C: per-bucket counting sort -> final CSR + offs.
//      csr.x = src | (dst_local8 << 16)  (src < 65536 for this problem) ----
__global__ __launch_bounds__(256) void passC_kernel(const int4* __restrict__ ebuf,
                                                    const int* __restrict__ bb0,
                                                    int2* __restrict__ csr,
                                                    int* __restrict__ offs,
                                                    int N, int E, int K) {
    __shared__ int ldeg[256];
    __shared__ int sh[256];
    __shared__ int lofs[256];
    int b = blockIdx.x, t = threadIdx.x;
    int gb0 = bb0[b], gb1 = bb0[b + 1];
    int cnt = gb1 - gb0;
    int base = b << 8;
    ldeg[t] = 0;
    __syncthreads();
    for (int i = t; i < cnt; i += 256)
        atomicAdd(&ldeg[ebuf[gb0 + i].z & 255], 1);
    __syncthreads();
    int v = ldeg[t];
    sh[t] = v;
    __syncthreads();
    #pragma unroll
    for (int d = 1; d < 256; d <<= 1) {
        int add = (t >= d) ? sh[t - d] : 0;
        __syncthreads();
        sh[t] += add;
        __syncthreads();
    }
    lofs[t] = sh[t] - v;                      // exclusive local offset (also cursor below)
    int nInB = min(256, N - base);
    if (t < nInB) offs[base + t] = gb0 + lofs[t];
    if (b == K - 1 && t == 0) offs[N] = E;
    __syncthreads();
    for (int i = t; i < cnt; i += 256) {
        int4 r = ebuf[gb0 + i];
        int d = r.z & 255;
        int pos = atomicAdd(&lofs[d], 1);     // reuse lofs as cursor
        csr[gb0 + pos] = make_int2(r.x | (d << 16), r.y);
    }
}

// Fused layer, edge-parallel bucket version.
// Block b owns nodes [b*64, b*64+64) and their contiguous CSR edge range.
// 16 groups x 16 lanes; lane l holds channels 4l..4l+3.
__global__ __launch_bounds__(256) void agg_bucket_kernel(const float* __restrict__ prev,
                                                         const int2* __restrict__ csr,
                                                         const int* __restrict__ offs,
                                                         const float* __restrict__ W,
                                                         const float* __restrict__ bias,
                                                         float* __restrict__ out, int N) {
    __shared__ float accum[64 * 65];   // padded rows: epilogue reads conflict-free
    __shared__ float Wl[64 * 64];
    __shared__ float bl[64];
    const int tid = threadIdx.x;
    for (int i = tid; i < 64 * 65; i += 256) accum[i] = 0.f;
    for (int i = tid; i < 64 * 64; i += 256) Wl[i] = W[i];
    if (tid < 64) bl[tid] = bias[tid];
    __syncthreads();

    const int nb0 = blockIdx.x * 64;
    const int nb1 = min(N, nb0 + 64);
    const int eb0 = offs[nb0], eb1 = offs[nb1];
    const int total = eb1 - eb0;

    const int grp = tid >> 4;        // 0..15
    const int l = tid & 15;          // channel lane
    const int chunk = (total + 15) >> 4;
    int gs = eb0 + grp * chunk;
    int ge = min(eb1, gs + chunk);

    int curd = -1;
    float4 acc = make_float4(0.f, 0.f, 0.f, 0.f);

    #define MERGE(R, V)                                                        \
        {                                                                      \
            int d_ = ((R).x >> 16) & 63;                                       \
            float w_ = __int_as_float((R).y);                                  \
            if (d_ != curd) {                                                  \
                if (curd >= 0) {                                               \
                    atomicAdd(&accum[curd * 65 + 4 * l + 0], acc.x);           \
                    atomicAdd(&accum[curd * 65 + 4 * l + 1], acc.y);           \
                    atomicAdd(&accum[curd * 65 + 4 * l + 2], acc.z);           \
                    atomicAdd(&accum[curd * 65 + 4 * l + 3], acc.w);           \
                }                                                              \
                curd = d_;                                                     \
                acc = make_float4(0.f, 0.f, 0.f, 0.f);                         \
            }                                                                  \
            acc.x = fmaf(w_, (V).x, acc.x);                                    \
            acc.y = fmaf(w_, (V).y, acc.y);                                    \
            acc.z = fmaf(w_, (V).z, acc.z);                                    \
            acc.w = fmaf(w_, (V).w, acc.w);                                    \
        }

    int e = gs;
    for (; e + 4 <= ge; e += 4) {
        // 4 independent gathers in flight, then in-order merge
        int2 r0 = csr[e + 0];
        int2 r1 = csr[e + 1];
        int2 r2 = csr[e + 2];
        int2 r3 = csr[e + 3];
        const float4 v0 = *reinterpret_cast<const float4*>(prev + (size_t)(r0.x & 0xFFFF) * 64 + l * 4);
        const float4 v1 = *reinterpret_cast<const float4*>(prev + (size_t)(r1.x & 0xFFFF) * 64 + l * 4);
        const float4 v2 = *reinterpret_cast<const float4*>(prev + (size_t)(r2.x & 0xFFFF) * 64 + l * 4);
        const float4 v3 = *reinterpret_cast<const float4*>(prev + (size_t)(r3.x & 0xFFFF) * 64 + l * 4);
        MERGE(r0, v0);
        MERGE(r1, v1);
        MERGE(r2, v2);
        MERGE(r3, v3);
    }
    for (; e < ge; ++e) {
        int2 r = csr[e];
        const float4 v = *reinterpret_cast<const float4*>(prev + (size_t)(r.x & 0xFFFF) * 64 + l * 4);
        MERGE(r, v);
    }
    if (curd >= 0) {
        atomicAdd(&accum[curd * 65 + 4 * l + 0], acc.x);
        atomicAdd(&accum[curd * 65 + 4 * l + 1], acc.y);
        atomicAdd(&accum[curd * 65 + 4 * l + 2], acc.z);
        atomicAdd(&accum[curd * 65 + 4 * l + 3], acc.w);
    }
    #undef MERGE
    __syncthreads();

    // Epilogue: 4 threads per node; thread computes output channels j0..j0+15.
    const int node = tid >> 2;
    const int j0 = (tid & 3) * 16;
    if (nb0 + node < nb1) {
        float o[16];
        #pragma unroll
        for (int jj = 0; jj < 16; ++jj) o[jj] = bl[j0 + jj];
        for (int k = 0; k < 64; ++k) {
            float a = accum[node * 65 + k];
            #pragma unroll
            for (int q = 0; q < 4; ++q) {
                const float4 wv = *reinterpret_cast<const float4*>(&Wl[k * 64 + j0 + q * 4]);
                o[q * 4 + 0] = fmaf(a, wv.x, o[q * 4 + 0]);
                o[q * 4 + 1] = fmaf(a, wv.y, o[q * 4 + 1]);
                o[q * 4 + 2] = fmaf(a, wv.z, o[q * 4 + 2]);
                o[q * 4 + 3] = fmaf(a, wv.w, o[q * 4 + 3]);
            }
        }
        float* op = out + (size_t)(nb0 + node) * 64 + j0;
        #pragma unroll
        for (int q = 0; q < 4; ++q) {
            float4 r;
            r.x = fmaxf(o[q * 4 + 0], 0.f);
            r.y = fmaxf(o[q * 4 + 1], 0.f);
            r.z = fmaxf(o[q * 4 + 2], 0.f);
            r.w = fmaxf(o[q * 4 + 3], 0.f);
            *reinterpret_cast<float4*>(op + q * 4) = r;
        }
    }
}

// Mean-pool stage 1: sorted batch -> register run-length accumulate, atomic flush.
__global__ __launch_bounds__(256) void pool_kernel(const float* __restrict__ a,
                                                   const int* __restrict__ batch,
                                                   float* __restrict__ sums,
                                                   float* __restrict__ cnts, int N) {
    int c = threadIdx.x & 63;
    int sub = threadIdx.x >> 6;   // 0..3
    int chunk = (N + gridDim.x - 1) / gridDim.x;
    int start = blockIdx.x * chunk;
    int end = min(N, start + chunk);
    int curg = -1;
    float acc = 0.f, cacc = 0.f;
    for (int n = start + sub; n < end; n += 4) {
        int g = batch[n];
        if (g != curg) {
            if (curg >= 0) {
                atomicAdd(&sums[curg * 64 + c], acc);
                if (c == 0) atomicAdd(&cnts[curg], cacc);
            }
            curg = g; acc = 0.f; cacc = 0.f;
        }
        acc += a[(size_t)n * 64 + c];
        cacc += 1.f;
    }
    if (curg >= 0) {
        atomicAdd(&sums[curg * 64 + c], acc);
        if (c == 0) atomicAdd(&cnts[curg], cacc);
    }
}

// MLP head: pooled[G][64] -> relu(@lw1 64x32) -> relu(@lw2 32x16) -> @lw3 16x1
__global__ __launch_bounds__(256) void head_kernel(const float* __restrict__ sums,
                                                   const float* __restrict__ cnts,
                                                   const float* __restrict__ lw1,
                                                   const float* __restrict__ lb1,
                                                   const float* __restrict__ lw2,
                                                   const float* __restrict__ lb2,
                                                   const float* __restrict__ lw3,
                                                   const float* __restrict__ lb3,
                                                   float* __restrict__ out, int G) {
    __shared__ float pooled[64 * 64];
    __shared__ float z1[64 * 32];
    __shared__ float z2[64 * 16];
    int tid = threadIdx.x;
    for (int i = tid; i < G * 64; i += 256) {
        int g = i >> 6;
        float cn = cnts[g];
        cn = (cn < 1.f) ? 1.f : cn;
        pooled[i] = sums[i] / cn;
    }
    __syncthreads();
    for (int i = tid; i < G * 32; i += 256) {
        int g = i >> 5, j = i & 31;
        float acc = lb1[j];
        #pragma unroll
        for (int k = 0; k < 64; ++k) acc = fmaf(pooled[g * 64 + k], lw1[k * 32 + j], acc);
        z1[i] = fmaxf(acc, 0.f);
    }
    __syncthreads();
    for (int i = tid; i < G * 16; i += 256) {
        int g = i >> 4, j = i & 15;
        float acc = lb2[j];
        #pragma unroll
        for (int k = 0; k < 32; ++k) acc = fmaf(z1[g * 32 + k], lw2[k * 16 + j], acc);
        z2[i] = fmaxf(acc, 0.f);
    }
    __syncthreads();
    if (tid < G) {
        float acc = lb3[0];
        #pragma unroll
        for (int k = 0; k < 16; ++k) acc = fmaf(z2[tid * 16 + k], lw3[k], acc);
        out[tid] = acc;
    }
}

static inline size_t align256(size_t x) { return (x + 255) & ~(size_t)255; }

extern "C" void kernel_launch(void* const* d_in, const int* in_sizes, int n_in,
                              void* d_out, int out_size, void* d_ws, size_t ws_size,
                              hipStream_t stream) {
    const float* x     = (const float*)d_in[0];
    const int*   ei    = (const int*)d_in[1];     // (2,E): [0..E)=src, [E..2E)=dst
    const float* ew    = (const float*)d_in[2];
    const int*   batch = (const int*)d_in[3];
    const float* W1 = (const float*)d_in[4];
    const float* b1 = (const float*)d_in[5];
    const float* W2 = (const float*)d_in[6];
    const float* b2 = (const float*)d_in[7];
    const float* W3 = (const float*)d_in[8];
    const float* b3 = (const float*)d_in[9];
    const float* lw1 = (const float*)d_in[10];
    const float* lb1 = (const float*)d_in[11];
    const float* lw2 = (const float*)d_in[12];
    const float* lb2 = (const float*)d_in[13];
    const float* lw3 = (const float*)d_in[14];
    const float* lb3 = (const float*)d_in[15];
    float* out = (float*)d_out;

    const int N = in_sizes[0] / 64;
    const int E = in_sizes[2];
    const int G = out_size;
    const int K = (N + 255) >> 8;          // buckets of 256 nodes
    const int chunk = (E + KNBLK - 1) / KNBLK;

    // Workspace carve
    char* w = (char*)d_ws;
    size_t off = 0;
    auto carve = [&](size_t bytes) -> void* {
        void* p = w + off;
        off = align256(off + bytes);
        return p;
    };
    float* bufA   = (float*)carve((size_t)N * 64 * 4);   // also aliases ebuf (dead before agg1)
    float* bufB   = (float*)carve((size_t)N * 64 * 4);
    int2*  csr    = (int2*)carve((size_t)E * 8);
    int*   counts = (int*)carve((size_t)KNBLK * K * 4);
    int*   btot   = (int*)carve((size_t)K * 4);
    int*   bb0    = (int*)carve((size_t)(K + 1) * 4);
    int*   offs   = (int*)carve((size_t)(N + 1) * 4);
    float* sums   = (float*)carve((size_t)G * 64 * 4);
    float* cnts   = (float*)carve((size_t)G * 4);
    int4*  ebuf   = (int4*)bufA;                         // 800K*16B = 12.8MB fits in bufA
    (void)ws_size; (void)n_in;

    hipMemsetAsync(sums, 0, (size_t)G * 64 * 4, stream);
    hipMemsetAsync(cnts, 0, (size_t)G * 4, stream);

    // ---- CSR build: bucketed counting sort (dense writes throughout) ----
    histA_kernel <<<KNBLK, 256, 0, stream>>>(ei, counts, E, K, chunk);
    scanB1_kernel<<<K,     256, 0, stream>>>(counts, btot, K);
    scanB2_kernel<<<1,     256, 0, stream>>>(btot, bb0, K);
    passB_kernel <<<KNBLK, 256, 0, stream>>>(ei, ew, counts, bb0, ebuf, E, K, chunk);
    passC_kernel <<<K,     256, 0, stream>>>(ebuf, bb0, csr, offs, N, E, K);

    const int AGGB = (N + 63) / 64;

    // ---- 3 fused layers: agg (raw features) -> @W + b -> relu ----
    agg_bucket_kernel<<<AGGB, 256, 0, stream>>>(x,    csr, offs, W1, b1, bufA, N);
    agg_bucket_kernel<<<AGGB, 256, 0, stream>>>(bufA, csr, offs, W2, b2, bufB, N);
    agg_bucket_kernel<<<AGGB, 256, 0, stream>>>(bufB, csr, offs, W3, b3, bufA, N);

    // ---- pool + head ----
    pool_kernel<<<1024, 256, 0, stream>>>(bufA, batch, sums, cnts, N);
    head_kernel<<<1, 256, 0, stream>>>(sums, cnts, lw1, lb1, lw2, lb2, lw3, lb3, out, G);
}

// Round 12
// 186.623 us; speedup vs baseline: 1.3549x; 1.1731x over previous
//
#include <hip/hip_runtime.h>
#include <hip/hip_bf16.h>
#include <hip/hip_fp16.h>

// GCN regressor: 3x GCNConv(64->64, normalize=False) + mean-pool + MLP(64->32->16->1)
// Round 11 kernel (resubmitted unchanged after container failure):
// REVERT to round-6 agg structure (16 lanes/node, x4 unroll — best measured)
// + fp16 activation table for the gather:
//   row = 128B = 2 cache lines per gather (was 4); table 6.4MB (~1 XCD L2).
//   All accumulation fp32; only stored h is fp16. x converted once.
// Build passes = round-6 counting sort (passC stores plain src again).

#define HID 64
#define KNBLK 256

// ---- pass A: per-block, per-bucket histogram. bucket = dst >> 8 ----
__global__ __launch_bounds__(256) void histA_kernel(const int* __restrict__ ei,
                                                    int* __restrict__ counts,
                                                    int E, int K, int chunk) {
    __shared__ int hist[256];
    int t = threadIdx.x, b = blockIdx.x;
    hist[t] = 0;
    __syncthreads();
    int s = b * chunk, e1 = min(E, s + chunk);
    for (int i = s + t; i < e1; i += 256)
        atomicAdd(&hist[ei[E + i] >> 8], 1);
    __syncthreads();
    if (t < K) counts[b * K + t] = hist[t];
}

// ---- scan B1: per bucket k, exclusive scan of counts[blk][k] over blk=0..255 ----
__global__ __launch_bounds__(256) void scanB1_kernel(int* __restrict__ counts,
                                                     int* __restrict__ btot, int K) {
    __shared__ int sh[256];
    int k = blockIdx.x, t = threadIdx.x;
    int v = counts[t * K + k];
    sh[t] = v;
    __syncthreads();
    #pragma unroll
    for (int d = 1; d < 256; d <<= 1) {
        int add = (t >= d) ? sh[t - d] : 0;
        __syncthreads();
        sh[t] += add;
        __syncthreads();
    }
    counts[t * K + k] = sh[t] - v;
    if (t == 255) btot[k] = sh[255];
}

// ---- scan B2: exclusive scan of bucket totals -> bucket base offsets bb0[0..K] ----
__global__ __launch_bounds__(256) void scanB2_kernel(const int* __restrict__ btot,
                                                     int* __restrict__ bb0, int K) {
    __shared__ int sh[256];
    int t = threadIdx.x;
    int v = (t < K) ? btot[t] : 0;
    sh[t] = v;
    __syncthreads();
    #pragma unroll
    for (int d = 1; d < 256; d <<= 1) {
        int add = (t >= d) ? sh[t - d] : 0;
        __syncthreads();
        sh[t] += add;
        __syncthreads();
    }
    if (t < K) bb0[t] = sh[t] - v;
    if (t == 255) bb0[K] = sh[255];
}

// ---- pass B: scatter edges to bucket-partitioned ebuf (dense slice writes) ----
__global__ __launch_bounds__(256) void passB_kernel(const int* __restrict__ ei,
                                                    const float* __restrict__ ew,
                                                    const int* __restrict__ counts,
                                                    const int* __restrict__ bb0,
                                                    int4* __restrict__ ebuf,
                                                    int E, int K, int chunk) {
    __shared__ int lcur[256];
    int t = threadIdx.x, b = blockIdx.x;
    lcur[t] = 0;
    __syncthreads();
    int s = b * chunk, e1 = min(E, s + chunk);
    for (int i = s + t; i < e1; i += 256) {
        int src = ei[i];
        int dst = ei[E + i];
        float w = ew[i];
        int k = dst >> 8;
        int idx = atomicAdd(&lcur[k], 1);
        int slot = bb0[k] + counts[b * K + k] + idx;
        ebuf[slot] = make_int4(src, __float_as_int(w), dst, 0);
    }
}

// ---- pass C: per-bucket counting sort -> final CSR (int2{src,wbits}) + offs ----
__global__ __launch_bounds__(256) void passC_kernel(const int4* __restrict__ ebuf,
                                                    const int* __restrict__ bb0,
                                                    int2* __restrict__ csr,
                                                    int* __restrict__ offs,
                                                    int N, int E, int K) {
    __shared__ int ldeg[256];
    __shared__ int sh[256];
    __shared__ int lofs[256];
    int b = blockIdx.x, t = threadIdx.x;
    int gb0 = bb0[b], gb1 = bb0[b + 1];
    int cnt = gb1 - gb0;
    int base = b << 8;
    ldeg[t] = 0;
    __syncthreads();
    for (int i = t; i < cnt; i += 256)
        atomicAdd(&ldeg[ebuf[gb0 + i].z & 255], 1);
    __syncthreads();
    int v = ldeg[t];
    sh[t] = v;
    __syncthreads();
    #pragma unroll
    for (int d = 1; d < 256; d <<= 1) {
        int add = (t >= d) ? sh[t - d] : 0;
        __syncthreads();
        sh[t] += add;
        __syncthreads();
    }
    lofs[t] = sh[t] - v;
    int nInB = min(256, N - base);
    if (t < nInB) offs[base + t] = gb0 + lofs[t];
    if (b == K - 1 && t == 0) offs[N] = E;
    __syncthreads();
    for (int i = t; i < cnt; i += 256) {
        int4 r = ebuf[gb0 + i];
        int d = r.z & 255;
        int pos = atomicAdd(&lofs[d], 1);
        csr[gb0 + pos] = make_int2(r.x, r.y);
    }
}

// ---- fp32 -> fp16 conversion (x table), 4 elems/thread ----
__global__ __launch_bounds__(256) void conv_kernel(const float* __restrict__ in,
                                                   __half* __restrict__ out, int n4) {
    int i = blockIdx.x * 256 + threadIdx.x;
    if (i < n4) {
        const float4 v = *reinterpret_cast<const float4*>(in + (size_t)i * 4);
        __half2 a = __float22half2_rn(make_float2(v.x, v.y));
        __half2 b = __float22half2_rn(make_float2(v.z, v.w));
        uint2 u;
        u.x = __builtin_bit_cast(unsigned int, a);
        u.y = __builtin_bit_cast(unsigned int, b);
        *reinterpret_cast<uint2*>(out + (size_t)i * 4) = u;
    }
}

// Fused layer: out[n][:] = relu( (sum_{e in CSR(n)} w_e * prev[src_e][:]) @ W + b )
// 16 lanes/node; lane l owns channels 4l..4l+3 (8B fp16 load). fp32 accumulate.
// Edge loop unrolled x4 for MLP. W in LDS; shfl-broadcast epilogue. fp16 store.
__global__ __launch_bounds__(256) void agg_fused_kernel(const __half* __restrict__ prev,
                                                        const int2* __restrict__ csr,
                                                        const int* __restrict__ offs,
                                                        const float* __restrict__ W,
                                                        const float* __restrict__ bias,
                                                        __half* __restrict__ out, int N) {
    __shared__ float Wl[64 * 64];
    __shared__ float bl[64];
    for (int i = threadIdx.x; i < 64 * 64; i += 256) Wl[i] = W[i];
    if (threadIdx.x < 64) bl[threadIdx.x] = bias[threadIdx.x];
    __syncthreads();

    int g = (blockIdx.x * 256 + threadIdx.x) >> 4;   // node
    int l = threadIdx.x & 15;                        // lane in group
    if (g >= N) return;

    int e0 = offs[g], e1 = offs[g + 1];
    float4 acc = make_float4(0.f, 0.f, 0.f, 0.f);

    #define GLOAD(R, F0, F1)                                                         \
        const uint2 u##F0 = *reinterpret_cast<const uint2*>(                         \
            prev + (size_t)(R).x * 64 + l * 4);                                      \
        const float2 F0 = __half22float2(__builtin_bit_cast(__half2, u##F0.x));      \
        const float2 F1 = __half22float2(__builtin_bit_cast(__half2, u##F0.y));

    int e = e0;
    for (; e + 4 <= e1; e += 4) {
        int2 r0 = csr[e + 0];
        int2 r1 = csr[e + 1];
        int2 r2 = csr[e + 2];
        int2 r3 = csr[e + 3];
        GLOAD(r0, fa0, fa1);
        GLOAD(r1, fb0, fb1);
        GLOAD(r2, fc0, fc1);
        GLOAD(r3, fd0, fd1);
        const float w0 = __int_as_float(r0.y);
        const float w1 = __int_as_float(r1.y);
        const float w2 = __int_as_float(r2.y);
        const float w3 = __int_as_float(r3.y);
        acc.x = fmaf(w0, fa0.x, acc.x); acc.y = fmaf(w0, fa0.y, acc.y);
        acc.z = fmaf(w0, fa1.x, acc.z); acc.w = fmaf(w0, fa1.y, acc.w);
        acc.x = fmaf(w1, fb0.x, acc.x); acc.y = fmaf(w1, fb0.y, acc.y);
        acc.z = fmaf(w1, fb1.x, acc.z); acc.w = fmaf(w1, fb1.y, acc.w);
        acc.x = fmaf(w2, fc0.x, acc.x); acc.y = fmaf(w2, fc0.y, acc.y);
        acc.z = fmaf(w2, fc1.x, acc.z); acc.w = fmaf(w2, fc1.y, acc.w);
        acc.x = fmaf(w3, fd0.x, acc.x); acc.y = fmaf(w3, fd0.y, acc.y);
        acc.z = fmaf(w3, fd1.x, acc.z); acc.w = fmaf(w3, fd1.y, acc.w);
    }
    for (; e < e1; ++e) {
        int2 r = csr[e];
        GLOAD(r, fe0, fe1);
        const float w = __int_as_float(r.y);
        acc.x = fmaf(w, fe0.x, acc.x);
        acc.y = fmaf(w, fe0.y, acc.y);
        acc.z = fmaf(w, fe1.x, acc.z);
        acc.w = fmaf(w, fe1.y, acc.w);
    }
    #undef GLOAD

    const float b0 = bl[l * 4 + 0], b1_ = bl[l * 4 + 1];
    const float b2_ = bl[l * 4 + 2], b3_ = bl[l * 4 + 3];
    float4 o = make_float4(b0, b1_, b2_, b3_);
    #pragma unroll
    for (int k2 = 0; k2 < 16; ++k2) {
        float c0 = __shfl(acc.x, k2, 16);
        float c1 = __shfl(acc.y, k2, 16);
        float c2 = __shfl(acc.z, k2, 16);
        float c3 = __shfl(acc.w, k2, 16);
        const float4 w0 = *reinterpret_cast<const float4*>(Wl + (4 * k2 + 0) * 64 + l * 4);
        const float4 w1 = *reinterpret_cast<const float4*>(Wl + (4 * k2 + 1) * 64 + l * 4);
        const float4 w2 = *reinterpret_cast<const float4*>(Wl + (4 * k2 + 2) * 64 + l * 4);
        const float4 w3 = *reinterpret_cast<const float4*>(Wl + (4 * k2 + 3) * 64 + l * 4);
        o.x = fmaf(c0, w0.x, o.x); o.y = fmaf(c0, w0.y, o.y);
        o.z = fmaf(c0, w0.z, o.z); o.w = fmaf(c0, w0.w, o.w);
        o.x = fmaf(c1, w1.x, o.x); o.y = fmaf(c1, w1.y, o.y);
        o.z = fmaf(c1, w1.z, o.z); o.w = fmaf(c1, w1.w, o.w);
        o.x = fmaf(c2, w2.x, o.x); o.y = fmaf(c2, w2.y, o.y);
        o.z = fmaf(c2, w2.z, o.z); o.w = fmaf(c2, w2.w, o.w);
        o.x = fmaf(c3, w3.x, o.x); o.y = fmaf(c3, w3.y, o.y);
        o.z = fmaf(c3, w3.z, o.z); o.w = fmaf(c3, w3.w, o.w);
    }
    __half2 oa = __float22half2_rn(make_float2(fmaxf(o.x, 0.f), fmaxf(o.y, 0.f)));
    __half2 ob = __float22half2_rn(make_float2(fmaxf(o.z, 0.f), fmaxf(o.w, 0.f)));
    uint2 u;
    u.x = __builtin_bit_cast(unsigned int, oa);
    u.y = __builtin_bit_cast(unsigned int, ob);
    *reinterpret_cast<uint2*>(out + (size_t)g * 64 + l * 4) = u;
}

// Mean-pool stage 1 (fp16 input): sorted batch -> register run-length accumulate.
__global__ __launch_bounds__(256) void pool_kernel(const __half* __restrict__ a,
                                                   const int* __restrict__ batch,
                                                   float* __restrict__ sums,
                                                   float* __restrict__ cnts, int N) {
    int c = threadIdx.x & 63;
    int sub = threadIdx.x >> 6;   // 0..3
    int chunk = (N + gridDim.x - 1) / gridDim.x;
    int start = blockIdx.x * chunk;
    int end = min(N, start + chunk);
    int curg = -1;
    float acc = 0.f, cacc = 0.f;
    for (int n = start + sub; n < end; n += 4) {
        int g = batch[n];
        if (g != curg) {
            if (curg >= 0) {
                atomicAdd(&sums[curg * 64 + c], acc);
                if (c == 0) atomicAdd(&cnts[curg], cacc);
            }
            curg = g; acc = 0.f; cacc = 0.f;
        }
        acc += __half2float(a[(size_t)n * 64 + c]);
        cacc += 1.f;
    }
    if (curg >= 0) {
        atomicAdd(&sums[curg * 64 + c], acc);
        if (c == 0) atomicAdd(&cnts[curg], cacc);
    }
}

// MLP head: pooled[G][64] -> relu(@lw1 64x32) -> relu(@lw2 32x16) -> @lw3 16x1
__global__ __launch_bounds__(256) void head_kernel(const float* __restrict__ sums,
                                                   const float* __restrict__ cnts,
                                                   const float* __restrict__ lw1,
                                                   const float* __restrict__ lb1,
                                                   const float* __restrict__ lw2,
                                                   const float* __restrict__ lb2,
                                                   const float* __restrict__ lw3,
                                                   const float* __restrict__ lb3,
                                                   float* __restrict__ out, int G) {
    __shared__ float pooled[64 * 64];
    __shared__ float z1[64 * 32];
    __shared__ float z2[64 * 16];
    int tid = threadIdx.x;
    for (int i = tid; i < G * 64; i += 256) {
        int g = i >> 6;
        float cn = cnts[g];
        cn = (cn < 1.f) ? 1.f : cn;
        pooled[i] = sums[i] / cn;
    }
    __syncthreads();
    for (int i = tid; i < G * 32; i += 256) {
        int g = i >> 5, j = i & 31;
        float acc = lb1[j];
        #pragma unroll
        for (int k = 0; k < 64; ++k) acc = fmaf(pooled[g * 64 + k], lw1[k * 32 + j], acc);
        z1[i] = fmaxf(acc, 0.f);
    }
    __syncthreads();
    for (int i = tid; i < G * 16; i += 256) {
        int g = i >> 4, j = i & 15;
        float acc = lb2[j];
        #pragma unroll
        for (int k = 0; k < 32; ++k) acc = fmaf(z1[g * 32 + k], lw2[k * 16 + j], acc);
        z2[i] = fmaxf(acc, 0.f);
    }
    __syncthreads();
    if (tid < G) {
        float acc = lb3[0];
        #pragma unroll
        for (int k = 0; k < 16; ++k) acc = fmaf(z2[tid * 16 + k], lw3[k], acc);
        out[tid] = acc;
    }
}

static inline size_t align256(size_t x) { return (x + 255) & ~(size_t)255; }

extern "C" void kernel_launch(void* const* d_in, const int* in_sizes, int n_in,
                              void* d_out, int out_size, void* d_ws, size_t ws_size,
                              hipStream_t stream) {
    const float* x     = (const float*)d_in[0];
    const int*   ei    = (const int*)d_in[1];     // (2,E): [0..E)=src, [E..2E)=dst
    const float* ew    = (const float*)d_in[2];
    const int*   batch = (const int*)d_in[3];
    const float* W1 = (const float*)d_in[4];
    const float* b1 = (const float*)d_in[5];
    const float* W2 = (const float*)d_in[6];
    const float* b2 = (const float*)d_in[7];
    const float* W3 = (const float*)d_in[8];
    const float* b3 = (const float*)d_in[9];
    const float* lw1 = (const float*)d_in[10];
    const float* lb1 = (const float*)d_in[11];
    const float* lw2 = (const float*)d_in[12];
    const float* lb2 = (const float*)d_in[13];
    const float* lw3 = (const float*)d_in[14];
    const float* lb3 = (const float*)d_in[15];
    float* out = (float*)d_out;

    const int N = in_sizes[0] / 64;
    const int E = in_sizes[2];
    const int G = out_size;
    const int K = (N + 255) >> 8;
    const int chunk = (E + KNBLK - 1) / KNBLK;

    // Workspace carve. xh+hA contiguous region doubles as ebuf (dead before use):
    //   xh: N*64*2 = 6.4MB, hA: 6.4MB  => 12.8MB >= E*16 = 12.8MB.
    char* w = (char*)d_ws;
    size_t off = 0;
    auto carve = [&](size_t bytes) -> void* {
        void* p = w + off;
        off = align256(off + bytes);
        return p;
    };
    __half* xh    = (__half*)carve((size_t)N * 64 * 2);
    __half* hA    = (__half*)carve((size_t)N * 64 * 2);
    __half* hB    = (__half*)carve((size_t)N * 64 * 2);
    int2*  csr    = (int2*)carve((size_t)E * 8);
    int*   counts = (int*)carve((size_t)KNBLK * K * 4);
    int*   btot   = (int*)carve((size_t)K * 4);
    int*   bb0    = (int*)carve((size_t)(K + 1) * 4);
    int*   offs   = (int*)carve((size_t)(N + 1) * 4);
    float* sums   = (float*)carve((size_t)G * 64 * 4);
    float* cnts   = (float*)carve((size_t)G * 4);
    int4*  ebuf   = (int4*)xh;     // spans xh+hA; dead after passC
    (void)ws_size; (void)n_in;

    hipMemsetAsync(sums, 0, (size_t)G * 64 * 4, stream);
    hipMemsetAsync(cnts, 0, (size_t)G * 4, stream);

    // ---- CSR build: bucketed counting sort (dense writes throughout) ----
    histA_kernel <<<KNBLK, 256, 0, stream>>>(ei, counts, E, K, chunk);
    scanB1_kernel<<<K,     256, 0, stream>>>(counts, btot, K);
    scanB2_kernel<<<1,     256, 0, stream>>>(btot, bb0, K);
    passB_kernel <<<KNBLK, 256, 0, stream>>>(ei, ew, counts, bb0, ebuf, E, K, chunk);
    passC_kernel <<<K,     256, 0, stream>>>(ebuf, bb0, csr, offs, N, E, K);

    // ---- x -> fp16 (after passC: xh aliases ebuf) ----
    const int n4 = N * 64 / 4;
    conv_kernel<<<(n4 + 255) / 256, 256, 0, stream>>>(x, xh, n4);

    const int AGG_BLOCKS = (int)(((size_t)N * 16 + 255) / 256);

    // ---- 3 fused layers: agg (fp16 gather, fp32 accum) -> @W + b -> relu ----
    agg_fused_kernel<<<AGG_BLOCKS, 256, 0, stream>>>(xh, csr, offs, W1, b1, hA, N);
    agg_fused_kernel<<<AGG_BLOCKS, 256, 0, stream>>>(hA, csr, offs, W2, b2, hB, N);
    agg_fused_kernel<<<AGG_BLOCKS, 256, 0, stream>>>(hB, csr, offs, W3, b3, hA, N);

    // ---- pool + head ----
    pool_kernel<<<1024, 256, 0, stream>>>(hA, batch, sums, cnts, N);
    head_kernel<<<1, 256, 0, stream>>>(sums, cnts, lw1, lb1, lw2, lb2, lw3, lb3, out, G);
}

// Round 14
// 165.908 us; speedup vs baseline: 1.5240x; 1.1249x over previous
//
#include <hip/hip_runtime.h>
#include <hip/hip_bf16.h>
#include <hip/hip_fp16.h>

// GCN regressor: 3x GCNConv(64->64, normalize=False) + mean-pool + MLP(64->32->16->1)
// Round 13 kernel (resubmitted unchanged after container failure):
//  - agg: 8 lanes/node, each lane loads uint4 = 8 fp16 channels (16B).
//    Row gather = 8 requests (was 16). 8 nodes/wave x unroll4 = 32 rows in flight.
//    Epilogue: width-8 shfl broadcast, W in LDS, fp16 store (16B/lane).
//  - build: ebuf packed to int2 {src|dst_local<<16, wbits} (src<65536):
//    passB writes 6.4MB (was 12.8), passC reads half.

#define HID 64
#define KNBLK 256

// ---- pass A: per-block, per-bucket histogram. bucket = dst >> 8 ----
__global__ __launch_bounds__(256) void histA_kernel(const int* __restrict__ ei,
                                                    int* __restrict__ counts,
                                                    int E, int K, int chunk) {
    __shared__ int hist[256];
    int t = threadIdx.x, b = blockIdx.x;
    hist[t] = 0;
    __syncthreads();
    int s = b * chunk, e1 = min(E, s + chunk);
    for (int i = s + t; i < e1; i += 256)
        atomicAdd(&hist[ei[E + i] >> 8], 1);
    __syncthreads();
    if (t < K) counts[b * K + t] = hist[t];
}

// ---- scan B1 ----
__global__ __launch_bounds__(256) void scanB1_kernel(int* __restrict__ counts,
                                                     int* __restrict__ btot, int K) {
    __shared__ int sh[256];
    int k = blockIdx.x, t = threadIdx.x;
    int v = counts[t * K + k];
    sh[t] = v;
    __syncthreads();
    #pragma unroll
    for (int d = 1; d < 256; d <<= 1) {
        int add = (t >= d) ? sh[t - d] : 0;
        __syncthreads();
        sh[t] += add;
        __syncthreads();
    }
    counts[t * K + k] = sh[t] - v;
    if (t == 255) btot[k] = sh[255];
}

// ---- scan B2 ----
__global__ __launch_bounds__(256) void scanB2_kernel(const int* __restrict__ btot,
                                                     int* __restrict__ bb0, int K) {
    __shared__ int sh[256];
    int t = threadIdx.x;
    int v = (t < K) ? btot[t] : 0;
    sh[t] = v;
    __syncthreads();
    #pragma unroll
    for (int d = 1; d < 256; d <<= 1) {
        int add = (t >= d) ? sh[t - d] : 0;
        __syncthreads();
        sh[t] += add;
        __syncthreads();
    }
    if (t < K) bb0[t] = sh[t] - v;
    if (t == 255) bb0[K] = sh[255];
}

// ---- pass B: scatter edges to bucket-partitioned ebuf (packed int2 records) ----
__global__ __launch_bounds__(256) void passB_kernel(const int* __restrict__ ei,
                                                    const float* __restrict__ ew,
                                                    const int* __restrict__ counts,
                                                    const int* __restrict__ bb0,
                                                    int2* __restrict__ ebuf,
                                                    int E, int K, int chunk) {
    __shared__ int lcur[256];
    int t = threadIdx.x, b = blockIdx.x;
    lcur[t] = 0;
    __syncthreads();
    int s = b * chunk, e1 = min(E, s + chunk);
    for (int i = s + t; i < e1; i += 256) {
        int src = ei[i];
        int dst = ei[E + i];
        float w = ew[i];
        int k = dst >> 8;
        int idx = atomicAdd(&lcur[k], 1);
        int slot = bb0[k] + counts[b * K + k] + idx;
        ebuf[slot] = make_int2(src | ((dst & 255) << 16), __float_as_int(w));
    }
}

// ---- pass C: per-bucket counting sort -> final CSR (int2{src,wbits}) + offs ----
__global__ __launch_bounds__(256) void passC_kernel(const int2* __restrict__ ebuf,
                                                    const int* __restrict__ bb0,
                                                    int2* __restrict__ csr,
                                                    int* __restrict__ offs,
                                                    int N, int E, int K) {
    __shared__ int ldeg[256];
    __shared__ int sh[256];
    __shared__ int lofs[256];
    int b = blockIdx.x, t = threadIdx.x;
    int gb0 = bb0[b], gb1 = bb0[b + 1];
    int cnt = gb1 - gb0;
    int base = b << 8;
    ldeg[t] = 0;
    __syncthreads();
    for (int i = t; i < cnt; i += 256)
        atomicAdd(&ldeg[(ebuf[gb0 + i].x >> 16) & 255], 1);
    __syncthreads();
    int v = ldeg[t];
    sh[t] = v;
    __syncthreads();
    #pragma unroll
    for (int d = 1; d < 256; d <<= 1) {
        int add = (t >= d) ? sh[t - d] : 0;
        __syncthreads();
        sh[t] += add;
        __syncthreads();
    }
    lofs[t] = sh[t] - v;
    int nInB = min(256, N - base);
    if (t < nInB) offs[base + t] = gb0 + lofs[t];
    if (b == K - 1 && t == 0) offs[N] = E;
    __syncthreads();
    for (int i = t; i < cnt; i += 256) {
        int2 r = ebuf[gb0 + i];
        int d = (r.x >> 16) & 255;
        int pos = atomicAdd(&lofs[d], 1);
        csr[gb0 + pos] = make_int2(r.x & 0xFFFF, r.y);
    }
}

// ---- fp32 -> fp16 conversion (x table), 4 elems/thread ----
__global__ __launch_bounds__(256) void conv_kernel(const float* __restrict__ in,
                                                   __half* __restrict__ out, int n4) {
    int i = blockIdx.x * 256 + threadIdx.x;
    if (i < n4) {
        const float4 v = *reinterpret_cast<const float4*>(in + (size_t)i * 4);
        __half2 a = __float22half2_rn(make_float2(v.x, v.y));
        __half2 b = __float22half2_rn(make_float2(v.z, v.w));
        uint2 u;
        u.x = __builtin_bit_cast(unsigned int, a);
        u.y = __builtin_bit_cast(unsigned int, b);
        *reinterpret_cast<uint2*>(out + (size_t)i * 4) = u;
    }
}

// Fused layer: out[n][:] = relu( (sum_{e in CSR(n)} w_e * prev[src_e][:]) @ W + b )
// 8 lanes/node; lane l owns channels 8l..8l+7 (one uint4 = 16B fp16 load).
// fp32 accumulate; x4 unroll; width-8 shfl epilogue; 16B fp16 store.
__global__ __launch_bounds__(256) void agg_fused_kernel(const __half* __restrict__ prev,
                                                        const int2* __restrict__ csr,
                                                        const int* __restrict__ offs,
                                                        const float* __restrict__ W,
                                                        const float* __restrict__ bias,
                                                        __half* __restrict__ out, int N) {
    __shared__ float Wl[64 * 64];
    __shared__ float bl[64];
    for (int i = threadIdx.x; i < 64 * 64; i += 256) Wl[i] = W[i];
    if (threadIdx.x < 64) bl[threadIdx.x] = bias[threadIdx.x];
    __syncthreads();

    int g = (blockIdx.x * 256 + threadIdx.x) >> 3;   // node (8 lanes each)
    int l = threadIdx.x & 7;                         // lane: channels 8l..8l+7
    if (g >= N) return;

    int e0 = offs[g], e1 = offs[g + 1];
    float acc[8] = {0.f, 0.f, 0.f, 0.f, 0.f, 0.f, 0.f, 0.f};

    #define GLOAD(R, U)                                                              \
        const uint4 U = *reinterpret_cast<const uint4*>(prev + (size_t)(R).x * 64 + l * 8);
    #define GACC(U, WW)                                                              \
        {                                                                            \
            const float2 f0 = __half22float2(__builtin_bit_cast(__half2, (U).x));    \
            const float2 f1 = __half22float2(__builtin_bit_cast(__half2, (U).y));    \
            const float2 f2 = __half22float2(__builtin_bit_cast(__half2, (U).z));    \
            const float2 f3 = __half22float2(__builtin_bit_cast(__half2, (U).w));    \
            acc[0] = fmaf((WW), f0.x, acc[0]); acc[1] = fmaf((WW), f0.y, acc[1]);    \
            acc[2] = fmaf((WW), f1.x, acc[2]); acc[3] = fmaf((WW), f1.y, acc[3]);    \
            acc[4] = fmaf((WW), f2.x, acc[4]); acc[5] = fmaf((WW), f2.y, acc[5]);    \
            acc[6] = fmaf((WW), f3.x, acc[6]); acc[7] = fmaf((WW), f3.y, acc[7]);    \
        }

    int e = e0;
    for (; e + 4 <= e1; e += 4) {
        int2 r0 = csr[e + 0];
        int2 r1 = csr[e + 1];
        int2 r2 = csr[e + 2];
        int2 r3 = csr[e + 3];
        GLOAD(r0, ua);
        GLOAD(r1, ub);
        GLOAD(r2, uc);
        GLOAD(r3, ud);
        GACC(ua, __int_as_float(r0.y));
        GACC(ub, __int_as_float(r1.y));
        GACC(uc, __int_as_float(r2.y));
        GACC(ud, __int_as_float(r3.y));
    }
    for (; e < e1; ++e) {
        int2 r = csr[e];
        GLOAD(r, ue);
        GACC(ue, __int_as_float(r.y));
    }
    #undef GLOAD
    #undef GACC

    float o[8];
    #pragma unroll
    for (int j = 0; j < 8; ++j) o[j] = bl[l * 8 + j];
    #pragma unroll
    for (int k2 = 0; k2 < 8; ++k2) {
        float c[8];
        #pragma unroll
        for (int j = 0; j < 8; ++j) c[j] = __shfl(acc[j], k2, 8);
        #pragma unroll
        for (int j = 0; j < 8; ++j) {
            const float4 wa = *reinterpret_cast<const float4*>(Wl + (8 * k2 + j) * 64 + l * 8);
            const float4 wb = *reinterpret_cast<const float4*>(Wl + (8 * k2 + j) * 64 + l * 8 + 4);
            o[0] = fmaf(c[j], wa.x, o[0]); o[1] = fmaf(c[j], wa.y, o[1]);
            o[2] = fmaf(c[j], wa.z, o[2]); o[3] = fmaf(c[j], wa.w, o[3]);
            o[4] = fmaf(c[j], wb.x, o[4]); o[5] = fmaf(c[j], wb.y, o[5]);
            o[6] = fmaf(c[j], wb.z, o[6]); o[7] = fmaf(c[j], wb.w, o[7]);
        }
    }
    uint4 u;
    u.x = __builtin_bit_cast(unsigned int,
          __float22half2_rn(make_float2(fmaxf(o[0], 0.f), fmaxf(o[1], 0.f))));
    u.y = __builtin_bit_cast(unsigned int,
          __float22half2_rn(make_float2(fmaxf(o[2], 0.f), fmaxf(o[3], 0.f))));
    u.z = __builtin_bit_cast(unsigned int,
          __float22half2_rn(make_float2(fmaxf(o[4], 0.f), fmaxf(o[5], 0.f))));
    u.w = __builtin_bit_cast(unsigned int,
          __float22half2_rn(make_float2(fmaxf(o[6], 0.f), fmaxf(o[7], 0.f))));
    *reinterpret_cast<uint4*>(out + (size_t)g * 64 + l * 8) = u;
}

// Mean-pool stage 1 (fp16 input): sorted batch -> register run-length accumulate.
__global__ __launch_bounds__(256) void pool_kernel(const __half* __restrict__ a,
                                                   const int* __restrict__ batch,
                                                   float* __restrict__ sums,
                                                   float* __restrict__ cnts, int N) {
    int c = threadIdx.x & 63;
    int sub = threadIdx.x >> 6;   // 0..3
    int chunk = (N + gridDim.x - 1) / gridDim.x;
    int start = blockIdx.x * chunk;
    int end = min(N, start + chunk);
    int curg = -1;
    float acc = 0.f, cacc = 0.f;
    for (int n = start + sub; n < end; n += 4) {
        int g = batch[n];
        if (g != curg) {
            if (curg >= 0) {
                atomicAdd(&sums[curg * 64 + c], acc);
                if (c == 0) atomicAdd(&cnts[curg], cacc);
            }
            curg = g; acc = 0.f; cacc = 0.f;
        }
        acc += __half2float(a[(size_t)n * 64 + c]);
        cacc += 1.f;
    }
    if (curg >= 0) {
        atomicAdd(&sums[curg * 64 + c], acc);
        if (c == 0) atomicAdd(&cnts[curg], cacc);
    }
}

// MLP head: pooled[G][64] -> relu(@lw1 64x32) -> relu(@lw2 32x16) -> @lw3 16x1
__global__ __launch_bounds__(256) void head_kernel(const float* __restrict__ sums,
                                                   const float* __restrict__ cnts,
                                                   const float* __restrict__ lw1,
                                                   const float* __restrict__ lb1,
                                                   const float* __restrict__ lw2,
                                                   const float* __restrict__ lb2,
                                                   const float* __restrict__ lw3,
                                                   const float* __restrict__ lb3,
                                                   float* __restrict__ out, int G) {
    __shared__ float pooled[64 * 64];
    __shared__ float z1[64 * 32];
    __shared__ float z2[64 * 16];
    int tid = threadIdx.x;
    for (int i = tid; i < G * 64; i += 256) {
        int g = i >> 6;
        float cn = cnts[g];
        cn = (cn < 1.f) ? 1.f : cn;
        pooled[i] = sums[i] / cn;
    }
    __syncthreads();
    for (int i = tid; i < G * 32; i += 256) {
        int g = i >> 5, j = i & 31;
        float acc = lb1[j];
        #pragma unroll
        for (int k = 0; k < 64; ++k) acc = fmaf(pooled[g * 64 + k], lw1[k * 32 + j], acc);
        z1[i] = fmaxf(acc, 0.f);
    }
    __syncthreads();
    for (int i = tid; i < G * 16; i += 256) {
        int g = i >> 4, j = i & 15;
        float acc = lb2[j];
        #pragma unroll
        for (int k = 0; k < 32; ++k) acc = fmaf(z1[g * 32 + k], lw2[k * 16 + j], acc);
        z2[i] = fmaxf(acc, 0.f);
    }
    __syncthreads();
    if (tid < G) {
        float acc = lb3[0];
        #pragma unroll
        for (int k = 0; k < 16; ++k) acc = fmaf(z2[tid * 16 + k], lw3[k], acc);
        out[tid] = acc;
    }
}

static inline size_t align256(size_t x) { return (x + 255) & ~(size_t)255; }

extern "C" void kernel_launch(void* const* d_in, const int* in_sizes, int n_in,
                              void* d_out, int out_size, void* d_ws, size_t ws_size,
                              hipStream_t stream) {
    const float* x     = (const float*)d_in[0];
    const int*   ei    = (const int*)d_in[1];     // (2,E): [0..E)=src, [E..2E)=dst
    const float* ew    = (const float*)d_in[2];
    const int*   batch = (const int*)d_in[3];
    const float* W1 = (const float*)d_in[4];
    const float* b1 = (const float*)d_in[5];
    const float* W2 = (const float*)d_in[6];
    const float* b2 = (const float*)d_in[7];
    const float* W3 = (const float*)d_in[8];
    const float* b3 = (const float*)d_in[9];
    const float* lw1 = (const float*)d_in[10];
    const float* lb1 = (const float*)d_in[11];
    const float* lw2 = (const float*)d_in[12];
    const float* lb2 = (const float*)d_in[13];
    const float* lw3 = (const float*)d_in[14];
    const float* lb3 = (const float*)d_in[15];
    float* out = (float*)d_out;

    const int N = in_sizes[0] / 64;
    const int E = in_sizes[2];
    const int G = out_size;
    const int K = (N + 255) >> 8;
    const int chunk = (E + KNBLK - 1) / KNBLK;

    // Workspace carve. ebuf (int2, 6.4MB) aliases xh (6.4MB; dead before conv).
    char* w = (char*)d_ws;
    size_t off = 0;
    auto carve = [&](size_t bytes) -> void* {
        void* p = w + off;
        off = align256(off + bytes);
        return p;
    };
    __half* xh    = (__half*)carve((size_t)N * 64 * 2);
    __half* hA    = (__half*)carve((size_t)N * 64 * 2);
    __half* hB    = (__half*)carve((size_t)N * 64 * 2);
    int2*  csr    = (int2*)carve((size_t)E * 8);
    int*   counts = (int*)carve((size_t)KNBLK * K * 4);
    int*   btot   = (int*)carve((size_t)K * 4);
    int*   bb0    = (int*)carve((size_t)(K + 1) * 4);
    int*   offs   = (int*)carve((size_t)(N + 1) * 4);
    float* sums   = (float*)carve((size_t)G * 64 * 4);
    float* cnts   = (float*)carve((size_t)G * 4);
    int2*  ebuf   = (int2*)xh;     // 800K*8B = 6.4MB fits in xh; dead after passC
    (void)ws_size; (void)n_in;

    hipMemsetAsync(sums, 0, (size_t)G * 64 * 4, stream);
    hipMemsetAsync(cnts, 0, (size_t)G * 4, stream);

    // ---- CSR build: bucketed counting sort (dense writes throughout) ----
    histA_kernel <<<KNBLK, 256, 0, stream>>>(ei, counts, E, K, chunk);
    scanB1_kernel<<<K,     256, 0, stream>>>(counts, btot, K);
    scanB2_kernel<<<1,     256, 0, stream>>>(btot, bb0, K);
    passB_kernel <<<KNBLK, 256, 0, stream>>>(ei, ew, counts, bb0, ebuf, E, K, chunk);
    passC_kernel <<<K,     256, 0, stream>>>(ebuf, bb0, csr, offs, N, E, K);

    // ---- x -> fp16 (after passC: xh aliases ebuf) ----
    const int n4 = N * 64 / 4;
    conv_kernel<<<(n4 + 255) / 256, 256, 0, stream>>>(x, xh, n4);

    const int AGG_BLOCKS = (int)(((size_t)N * 8 + 255) / 256);

    // ---- 3 fused layers: agg (fp16 gather, fp32 accum) -> @W + b -> relu ----
    agg_fused_kernel<<<AGG_BLOCKS, 256, 0, stream>>>(xh, csr, offs, W1, b1, hA, N);
    agg_fused_kernel<<<AGG_BLOCKS, 256, 0, stream>>>(hA, csr, offs, W2, b2, hB, N);
    agg_fused_kernel<<<AGG_BLOCKS, 256, 0, stream>>>(hB, csr, offs, W3, b3, hA, N);

    // ---- pool + head ----
    pool_kernel<<<1024, 256, 0, stream>>>(hA, batch, sums, cnts, N);
    head_kernel<<<1, 256, 0, stream>>>(sums, cnts, lw1, lb1, lw2, lb2, lw3, lb3, out, G);
}